// Round 9
// baseline (38.378 us; speedup 1.0000x reference)
//
#include <hip/hip_runtime.h>
#include <cstddef>
#include <type_traits>

#define BB 2
#define TT 4
#define LL 384
#define CZ 128
#define NBINS 39
#define NBOUND 38

typedef float f32x4 __attribute__((ext_vector_type(4)));

// One block per (b, i). 512 threads.
// LDS: Wd 19.5K + Wj 10.5K + meta 6K = 36 KB.
// R8 + nontemporal stores (output is never re-read; skip L2 allocate)
// + unroll 8 (deeper independent meta->gather->store chains).
__global__ __launch_bounds__(512) void tpe_kernel(
    const int*   __restrict__ aatype,   // [B,T,L] int32
    const float* __restrict__ coords,   // [B,T,L,3] f32
    const int*   __restrict__ tmask,    // [B,T,L] bool->int32
    const int*   __restrict__ rmask,    // [B,L] bool->int32
    const float* __restrict__ weight,   // [82,128] f32
    const float* __restrict__ bias,     // [128] f32
    float*       __restrict__ out)      // [B,L,L,128] f32
{
    __shared__ float Wd_sh[NBINS * CZ];  // raw rows 0..38
    __shared__ float Wj_sh[21 * CZ];     // rows 61..81
    __shared__ int4  meta_sh[LL];        // {pk01, pk23, 0, scale}; pk: bin|aa<<6|act<<11

    const int bi  = blockIdx.x;
    const int b   = bi / LL;
    const int i   = bi - b * LL;
    const int tid = threadIdx.x;
    const int bT  = b * TT;
    const int cg  = tid & 31;

    // ---- Issue staging loads into registers (commit deferred) ----
    // Flat float4 range: [0,1248) = Wd rows 0..38; [1248,1920) = Wj rows 61..81.
    const float4* wsrc = (const float4*)weight;
    float4 st0 = wsrc[tid];
    float4 st1 = wsrc[tid + 512];
    const int idx2 = tid + 1024;
    float4 st2 = (idx2 < 1248) ? wsrc[idx2] : wsrc[61 * 32 + idx2 - 1248];
    float4 st3;
    if (tid < 384) st3 = wsrc[61 * 32 + tid + 288];   // flat 1536..1919 -> wj 288..671

    // ---- Prefetch per-i row data (hides under meta compute) ----
    const f32x4* W4 = (const f32x4*)weight;
    const f32x4* B4 = (const f32x4*)bias;
    f32x4 wmb = W4[NBINS * (CZ / 4) + cg] + B4[cg];   // W_m + bias
    int icode = 0;
    f32x4 pr[TT];
    #pragma unroll
    for (int t = 0; t < TT; ++t) {
        icode |= (tmask[(bT + t) * LL + i] != 0) << t;
        int aa = aatype[(bT + t) * LL + i];
        aa = min(max(aa, 0), 20);
        pr[t] = W4[(NBINS + 1 + aa) * (CZ / 4) + cg];   // W_i row
    }
    #pragma unroll
    for (int t = 0; t < TT; ++t) pr[t] += wmb;          // pr = W_i + W_m + bias

    // ---- Per-j meta (one thread per j) while staging loads fly ----
    if (tid < LL) {
        #pragma clang fp contract(off)
        const int j  = tid;
        const int ri = rmask[b * LL + i];
        unsigned pks[TT] = {0, 0, 0, 0};
        int cnt = 0;
        #pragma unroll
        for (int t = 0; t < TT; ++t) {
            if (icode & (1 << t)) {                 // wave-uniform branch
                const int base = (bT + t) * LL;
                if (tmask[base + j] != 0) {
                    const float* ci = coords + (size_t)(base + i) * 3;
                    const float* cj = coords + (size_t)(base + j) * 3;
                    float dx = ci[0] - cj[0];
                    float dy = ci[1] - cj[1];
                    float dz = ci[2] - cj[2];
                    float s  = dx * dx + dy * dy;   // numpy order ((x+y)+z)
                    s = s + dz * dz;
                    float d = sqrtf(s);             // IEEE sqrt
                    int bin = 0;
                    #pragma unroll
                    for (int k = 0; k < NBOUND; ++k) {
                        // folded at compile time; matches np.linspace(f64).astype(f32)
                        float bnd = (float)(3.25 + (double)k * (47.5 / 37.0));
                        bin += (d > bnd) ? 1 : 0;   // searchsorted side='left'
                    }
                    int aa = aatype[base + j];
                    aa = min(max(aa, 0), 20);
                    pks[t] = (unsigned)(bin | (aa << 6) | (1 << 11));
                    ++cnt;
                }
            }
        }
        float scale = (ri != 0 && rmask[b * LL + j] != 0)
                      ? 1.0f / fmaxf((float)cnt, 1.0f) : 0.0f;
        int4 m;
        m.x = (int)(pks[0] | (pks[1] << 16));
        m.y = (int)(pks[2] | (pks[3] << 16));
        m.z = 0;
        m.w = __float_as_int(scale);
        meta_sh[j] = m;
    }

    // ---- Commit staged weights to LDS ----
    {
        float4* wd = (float4*)Wd_sh;
        float4* wj = (float4*)Wj_sh;
        wd[tid] = st0;
        wd[tid + 512] = st1;
        if (idx2 < 1248) wd[idx2] = st2; else wj[idx2 - 1248] = st2;
        if (tid < 384) wj[tid + 288] = st3;
    }
    __syncthreads();

    // ---- Phase 2: switch-specialized; guarded gathers; NT stores ----
    const int jj = tid >> 5;       // 0..15
    const f32x4* Wd4 = (const f32x4*)Wd_sh;
    const f32x4* Wj4 = (const f32x4*)Wj_sh;
    f32x4* outv = (f32x4*)(out + (size_t)(b * LL + i) * LL * CZ);

    auto run = [&](auto cmc) {
        constexpr int CM = decltype(cmc)::value;
        #pragma unroll 8
        for (int j = jj; j < LL; j += 16) {
            int4 m = meta_sh[j];                    // broadcast b128
            f32x4 acc = {0.f, 0.f, 0.f, 0.f};
            #pragma unroll
            for (int t = 0; t < TT; ++t) {
                if (CM & (1 << t)) {
                    unsigned h = (unsigned)(t < 2 ? m.x : m.y);
                    unsigned pk = (h >> ((t & 1) * 16)) & 0xFFFFu;
                    if (pk & 2048u) {               // uniform per 32-lane j-group
                        f32x4 a = Wd4[(pk & 63u) * (CZ / 4) + cg];        // W_d[bin]
                        f32x4 c = Wj4[((pk >> 6) & 31u) * (CZ / 4) + cg]; // W_j[aa]
                        acc += a + c + pr[t];
                    }
                }
            }
            f32x4 o = acc * __int_as_float(m.w);
            __builtin_nontemporal_store(o, &outv[j * (CZ / 4) + cg]);
        }
    };

    #define RUN_CASE(K) case K: run(std::integral_constant<int, K>{}); break;
    switch (icode) {
        RUN_CASE(0)  RUN_CASE(1)  RUN_CASE(2)  RUN_CASE(3)
        RUN_CASE(4)  RUN_CASE(5)  RUN_CASE(6)  RUN_CASE(7)
        RUN_CASE(8)  RUN_CASE(9)  RUN_CASE(10) RUN_CASE(11)
        RUN_CASE(12) RUN_CASE(13) RUN_CASE(14) RUN_CASE(15)
    }
    #undef RUN_CASE
}

extern "C" void kernel_launch(void* const* d_in, const int* in_sizes, int n_in,
                              void* d_out, int out_size, void* d_ws, size_t ws_size,
                              hipStream_t stream) {
    const int*   aatype = (const int*)d_in[0];
    const float* coords = (const float*)d_in[1];
    const int*   tmask  = (const int*)d_in[2];
    const int*   rmask  = (const int*)d_in[3];
    const float* weight = (const float*)d_in[4];
    const float* bias   = (const float*)d_in[5];
    float* out = (float*)d_out;

    dim3 grid(BB * LL);
    dim3 block(512);
    tpe_kernel<<<grid, block, 0, stream>>>(aatype, coords, tmask, rmask, weight, bias, out);
}

// Round 10
// 32.248 us; speedup vs baseline: 1.1901x; 1.1901x over previous
//
#include <hip/hip_runtime.h>
#include <cstddef>
#include <type_traits>

#define BB 2
#define TT 4
#define LL 384
#define CZ 128
#define NBINS 39
#define NBOUND 38

typedef float f32x4 __attribute__((ext_vector_type(4)));

// One block per (b, i). 512 threads.
// LDS: Wd 19.5K + Wj 10.5K + meta 6K = 36 KB.
// Best-measured configuration (R8, 32.25 us): deferred-staging prologue,
// switch-specialized phase 2, per-j-group guarded gathers, plain stores,
// unroll 4. NT stores and unroll 8 both regressed (R9: 38.4 us) - reverted.
__global__ __launch_bounds__(512) void tpe_kernel(
    const int*   __restrict__ aatype,   // [B,T,L] int32
    const float* __restrict__ coords,   // [B,T,L,3] f32
    const int*   __restrict__ tmask,    // [B,T,L] bool->int32
    const int*   __restrict__ rmask,    // [B,L] bool->int32
    const float* __restrict__ weight,   // [82,128] f32
    const float* __restrict__ bias,     // [128] f32
    float*       __restrict__ out)      // [B,L,L,128] f32
{
    __shared__ float Wd_sh[NBINS * CZ];  // raw rows 0..38
    __shared__ float Wj_sh[21 * CZ];     // rows 61..81
    __shared__ int4  meta_sh[LL];        // {pk01, pk23, 0, scale}; pk: bin|aa<<6|act<<11

    const int bi  = blockIdx.x;
    const int b   = bi / LL;
    const int i   = bi - b * LL;
    const int tid = threadIdx.x;
    const int bT  = b * TT;
    const int cg  = tid & 31;

    // ---- Issue staging loads into registers (commit deferred) ----
    // Flat float4 range: [0,1248) = Wd rows 0..38; [1248,1920) = Wj rows 61..81.
    const float4* wsrc = (const float4*)weight;
    float4 st0 = wsrc[tid];
    float4 st1 = wsrc[tid + 512];
    const int idx2 = tid + 1024;
    float4 st2 = (idx2 < 1248) ? wsrc[idx2] : wsrc[61 * 32 + idx2 - 1248];
    float4 st3;
    if (tid < 384) st3 = wsrc[61 * 32 + tid + 288];   // flat 1536..1919 -> wj 288..671

    // ---- Prefetch per-i row data (hides under meta compute) ----
    const f32x4* W4 = (const f32x4*)weight;
    const f32x4* B4 = (const f32x4*)bias;
    f32x4 wmb = W4[NBINS * (CZ / 4) + cg] + B4[cg];   // W_m + bias
    int icode = 0;
    f32x4 pr[TT];
    #pragma unroll
    for (int t = 0; t < TT; ++t) {
        icode |= (tmask[(bT + t) * LL + i] != 0) << t;
        int aa = aatype[(bT + t) * LL + i];
        aa = min(max(aa, 0), 20);
        pr[t] = W4[(NBINS + 1 + aa) * (CZ / 4) + cg];   // W_i row
    }
    #pragma unroll
    for (int t = 0; t < TT; ++t) pr[t] += wmb;          // pr = W_i + W_m + bias

    // ---- Per-j meta (one thread per j) while staging loads fly ----
    if (tid < LL) {
        #pragma clang fp contract(off)
        const int j  = tid;
        const int ri = rmask[b * LL + i];
        unsigned pks[TT] = {0, 0, 0, 0};
        int cnt = 0;
        #pragma unroll
        for (int t = 0; t < TT; ++t) {
            if (icode & (1 << t)) {                 // wave-uniform branch
                const int base = (bT + t) * LL;
                if (tmask[base + j] != 0) {
                    const float* ci = coords + (size_t)(base + i) * 3;
                    const float* cj = coords + (size_t)(base + j) * 3;
                    float dx = ci[0] - cj[0];
                    float dy = ci[1] - cj[1];
                    float dz = ci[2] - cj[2];
                    float s  = dx * dx + dy * dy;   // numpy order ((x+y)+z)
                    s = s + dz * dz;
                    float d = sqrtf(s);             // IEEE sqrt
                    int bin = 0;
                    #pragma unroll
                    for (int k = 0; k < NBOUND; ++k) {
                        // folded at compile time; matches np.linspace(f64).astype(f32)
                        float bnd = (float)(3.25 + (double)k * (47.5 / 37.0));
                        bin += (d > bnd) ? 1 : 0;   // searchsorted side='left'
                    }
                    int aa = aatype[base + j];
                    aa = min(max(aa, 0), 20);
                    pks[t] = (unsigned)(bin | (aa << 6) | (1 << 11));
                    ++cnt;
                }
            }
        }
        float scale = (ri != 0 && rmask[b * LL + j] != 0)
                      ? 1.0f / fmaxf((float)cnt, 1.0f) : 0.0f;
        int4 m;
        m.x = (int)(pks[0] | (pks[1] << 16));
        m.y = (int)(pks[2] | (pks[3] << 16));
        m.z = 0;
        m.w = __float_as_int(scale);
        meta_sh[j] = m;
    }

    // ---- Commit staged weights to LDS ----
    {
        float4* wd = (float4*)Wd_sh;
        float4* wj = (float4*)Wj_sh;
        wd[tid] = st0;
        wd[tid + 512] = st1;
        if (idx2 < 1248) wd[idx2] = st2; else wj[idx2 - 1248] = st2;
        if (tid < 384) wj[tid + 288] = st3;
    }
    __syncthreads();

    // ---- Phase 2: switch-specialized; gathers guarded by per-j active bit ----
    const int jj = tid >> 5;       // 0..15
    const f32x4* Wd4 = (const f32x4*)Wd_sh;
    const f32x4* Wj4 = (const f32x4*)Wj_sh;
    f32x4* outv = (f32x4*)(out + (size_t)(b * LL + i) * LL * CZ);

    auto run = [&](auto cmc) {
        constexpr int CM = decltype(cmc)::value;
        #pragma unroll 4
        for (int j = jj; j < LL; j += 16) {
            int4 m = meta_sh[j];                    // broadcast b128
            f32x4 acc = {0.f, 0.f, 0.f, 0.f};
            #pragma unroll
            for (int t = 0; t < TT; ++t) {
                if (CM & (1 << t)) {
                    unsigned h = (unsigned)(t < 2 ? m.x : m.y);
                    unsigned pk = (h >> ((t & 1) * 16)) & 0xFFFFu;
                    if (pk & 2048u) {               // uniform per 32-lane j-group
                        f32x4 a = Wd4[(pk & 63u) * (CZ / 4) + cg];        // W_d[bin]
                        f32x4 c = Wj4[((pk >> 6) & 31u) * (CZ / 4) + cg]; // W_j[aa]
                        acc += a + c + pr[t];
                    }
                }
            }
            outv[j * (CZ / 4) + cg] = acc * __int_as_float(m.w);
        }
    };

    #define RUN_CASE(K) case K: run(std::integral_constant<int, K>{}); break;
    switch (icode) {
        RUN_CASE(0)  RUN_CASE(1)  RUN_CASE(2)  RUN_CASE(3)
        RUN_CASE(4)  RUN_CASE(5)  RUN_CASE(6)  RUN_CASE(7)
        RUN_CASE(8)  RUN_CASE(9)  RUN_CASE(10) RUN_CASE(11)
        RUN_CASE(12) RUN_CASE(13) RUN_CASE(14) RUN_CASE(15)
    }
    #undef RUN_CASE
}

extern "C" void kernel_launch(void* const* d_in, const int* in_sizes, int n_in,
                              void* d_out, int out_size, void* d_ws, size_t ws_size,
                              hipStream_t stream) {
    const int*   aatype = (const int*)d_in[0];
    const float* coords = (const float*)d_in[1];
    const int*   tmask  = (const int*)d_in[2];
    const int*   rmask  = (const int*)d_in[3];
    const float* weight = (const float*)d_in[4];
    const float* bias   = (const float*)d_in[5];
    float* out = (float*)d_out;

    dim3 grid(BB * LL);
    dim3 block(512);
    tpe_kernel<<<grid, block, 0, stream>>>(aatype, coords, tmask, rmask, weight, bias, out);
}